// Round 5
// baseline (8118.342 us; speedup 1.0000x reference)
//
#include <hip/hip_runtime.h>
#include <hip/hip_bf16.h>
#include <hip/hip_cooperative_groups.h>

namespace cg = cooperative_groups;

typedef __bf16 bf16x8 __attribute__((ext_vector_type(8)));
typedef float f32x4 __attribute__((ext_vector_type(4)));

__device__ __forceinline__ unsigned short f2bf(float f) {
    unsigned int u = __builtin_bit_cast(unsigned int, f);
    u += 0x7FFFu + ((u >> 16) & 1u);
    return (unsigned short)(u >> 16);
}
__device__ __forceinline__ float bf2f(unsigned short s) {
    unsigned int u = ((unsigned int)s) << 16;
    return __builtin_bit_cast(float, u);
}

// ---------------- prep: x -> split bf16 hi/lo in MFMA B-fragment layout ----------------
// layout: [t(200)][nt(8)][kc(16)][lane(64)][e(8)]; batch = nt*16+(lane&15), k = kc*32+(lane>>4)*8+e
__global__ void prep_x(const float* __restrict__ x,
                       unsigned short* __restrict__ xh,
                       unsigned short* __restrict__ xl) {
    int g = blockIdx.x * 256 + threadIdx.x;   // 1,638,400 frags
    if (g >= 1638400) return;
    int lane = g & 63;
    int kc   = (g >> 6) & 15;
    int nt   = (g >> 10) & 7;
    int t    = g >> 13;
    int batch = nt * 16 + (lane & 15);
    int k = kc * 32 + (lane >> 4) * 8;
    const float* s = x + ((size_t)batch * 200 + t) * 512 + k;
    float4 v0 = *(const float4*)s;
    float4 v1 = *(const float4*)(s + 4);
    float vv[8] = {v0.x, v0.y, v0.z, v0.w, v1.x, v1.y, v1.z, v1.w};
    unsigned int ph[4], pl[4];
    #pragma unroll
    for (int j = 0; j < 4; ++j) {
        float a = vv[2*j], b = vv[2*j+1];
        unsigned short ha = f2bf(a), hb = f2bf(b);
        unsigned short la = f2bf(a - bf2f(ha)), lb = f2bf(b - bf2f(hb));
        ph[j] = (unsigned)ha | ((unsigned)hb << 16);
        pl[j] = (unsigned)la | ((unsigned)lb << 16);
    }
    ((uint4*)xh)[g] = make_uint4(ph[0], ph[1], ph[2], ph[3]);
    ((uint4*)xl)[g] = make_uint4(pl[0], pl[1], pl[2], pl[3]);
}

// ---------------- prep: weights -> per-CU LDS image blocks ----------------
// dst block per (wu = dir*2+layer, cu 0..63): 8192 frags of 16B (131072 B):
//   frag idx within block = mat*2048 + mt*1024 + kc*64 + lane
//   mat: 0=ihH 1=ihL 2=hhH 3=hhL; within frag: row r=lane&15, k=kc*32+(lane>>4)*8+e
//   global gate row = (2*mt + (r>>3))*512 + cu*8 + (r&7)
__global__ void prep_w(const float* __restrict__ W,     // [2][2048][512] f32
                       unsigned short* __restrict__ wprep,
                       int dir, int isHH) {
    int g = blockIdx.x * 256 + threadIdx.x;   // 262,144
    if (g >= 262144) return;
    int lane = g & 63;
    int kc   = (g >> 6) & 15;
    int mt   = (g >> 10) & 1;
    int cu   = (g >> 11) & 63;
    int l    = g >> 17;
    int r = lane & 15;
    int grow = (2 * mt + (r >> 3)) * 512 + cu * 8 + (r & 7);
    int k = kc * 32 + (lane >> 4) * 8;
    const float* s = W + ((size_t)l * 2048 + grow) * 512 + k;
    float4 v0 = *(const float4*)s;
    float4 v1 = *(const float4*)(s + 4);
    float vv[8] = {v0.x, v0.y, v0.z, v0.w, v1.x, v1.y, v1.z, v1.w};
    unsigned int ph[4], pl[4];
    #pragma unroll
    for (int j = 0; j < 4; ++j) {
        float a = vv[2*j], b = vv[2*j+1];
        unsigned short ha = f2bf(a), hb = f2bf(b);
        unsigned short la = f2bf(a - bf2f(ha)), lb = f2bf(b - bf2f(hb));
        ph[j] = (unsigned)ha | ((unsigned)hb << 16);
        pl[j] = (unsigned)la | ((unsigned)lb << 16);
    }
    size_t blk = ((size_t)(dir * 2 + l) * 64 + cu) * 8192;
    size_t fH = blk + (size_t)((isHH * 2 + 0) * 2048 + mt * 1024 + kc * 64 + lane);
    size_t fL = blk + (size_t)((isHH * 2 + 1) * 2048 + mt * 1024 + kc * 64 + lane);
    ((uint4*)wprep)[fH] = make_uint4(ph[0], ph[1], ph[2], ph[3]);
    ((uint4*)wprep)[fL] = make_uint4(pl[0], pl[1], pl[2], pl[3]);
}

__global__ void bsum_k(const float* __restrict__ bih_f, const float* __restrict__ bhh_f,
                       const float* __restrict__ bih_b, const float* __restrict__ bhh_b,
                       float* __restrict__ bsum) {
    int i = blockIdx.x * 256 + threadIdx.x;   // 8192 = [dir][l][2048]
    if (i < 8192) {
        int dir = i >> 12, rem = i & 4095;
        const float* bi = dir ? bih_b : bih_f;
        const float* bh = dir ? bhh_b : bhh_f;
        bsum[i] = bi[rem] + bh[rem];
    }
}

__global__ void reset_k(uint4* __restrict__ p) {  // zero h_hi | h_lo (2,097,152 B)
    int g = blockIdx.x * 256 + threadIdx.x;
    if (g < 131072) p[g] = make_uint4(0, 0, 0, 0);
}

// ---------------- persistent cooperative LSTM ----------------
// 256 WGs (1/CU) x 512 threads. unit = xcd>>1 (slot=unit>>1, dir=unit&1);
// CU owns 8 hidden units (hj0 = cu8*8): gate rows {q*512+hj0..+7}, all 128 batches.
// Waves: kh = wave&3 (K-split, kc = kh*4+kcl), nh = wave>>2 (batch half).
// Weights stay in LDS for all 200 steps; c-state in LDS; h ping-pongs in global
// (parity) in B-frag layout; grid.sync() per step.
__global__ void __launch_bounds__(512)
lstm_persist(const unsigned short* __restrict__ xh,
             const unsigned short* __restrict__ xl,
             const unsigned short* __restrict__ wprep,
             const float*          __restrict__ bsum,
             unsigned short*       __restrict__ h_hi,   // [(slot*2+parity)*2+dir] x 65536
             unsigned short*       __restrict__ h_lo,
             const int*            __restrict__ lens,
             float*                __restrict__ dout)   // [128][200][1024]
{
    extern __shared__ char smem[];
    float* exch = (float*)(smem + 131072);            // [kh4][row32][33] = 16,896 B
    float* cst  = (float*)(smem + 131072 + 16896);    // [u8][132] = 4,224 B
    cg::grid_group grid = cg::this_grid();

    const int bid  = blockIdx.x;
    const int xcd  = bid & 7;
    const int unit = xcd >> 1;
    const int slot = unit >> 1, dir = unit & 1;
    const int cu8  = ((xcd & 1) << 5) | (bid >> 3);   // 0..63
    const int hj0  = cu8 * 8;
    const int tid  = threadIdx.x;
    const int lane = tid & 63, wv = tid >> 6;
    const int kh = wv & 3, nh = wv >> 2;
    const int l15 = lane & 15;
    const int wsel = dir * 2 + slot;                  // dir-major, matches prep_w/bsum

    // ---- stage weights into LDS (one-time) ----
    {
        // FIX (round 4 bug): weight blocks are stored dir-major (dir*2+layer),
        // unit is slot-major (slot*2+dir). Use wsel, not unit.
        const uint4* src = (const uint4*)wprep + ((size_t)(wsel * 64 + cu8) * 8192);
        uint4* dst = (uint4*)smem;
        #pragma unroll
        for (int i = 0; i < 16; ++i) dst[tid + i * 512] = src[tid + i * 512];
    }
    for (int i = tid; i < 8 * 132; i += 512) cst[i] = 0.f;
    __syncthreads();

    // ---- loop invariants ----
    int lenv[4];
    #pragma unroll
    for (int nt = 0; nt < 4; ++nt) lenv[nt] = lens[(nh * 4 + nt) * 16 + l15];

    const int cu_u = tid >> 5, cu_b = tid & 31;       // cell role (tid < 256)
    float bias_c[4];
    int   len_c[4];
    if (tid < 256) {
        #pragma unroll
        for (int q = 0; q < 4; ++q) bias_c[q] = bsum[wsel * 2048 + q * 512 + hj0 + cu_u];
        #pragma unroll
        for (int c = 0; c < 4; ++c) {
            int gb = (cu_b < 16) ? (c * 16 + cu_b) : (64 + c * 16 + (cu_b - 16));
            len_c[c] = lens[gb];
        }
    }

    for (int tau = 0; tau <= 200; ++tau) {
        int t = slot ? (tau - 1) : tau;
        if (t >= 0 && t <= 199) {
            int t_eff = dir ? (199 - t) : t;
            int p_r = t & 1, p_w = 1 - p_r;

            const unsigned short* XH;
            const unsigned short* XL;
            if (slot == 0) {
                XH = xh + (size_t)t_eff * 65536;
                XL = xl + (size_t)t_eff * 65536;
            } else {
                int p_x = 1 - (t & 1);                 // layer0 wrote h_t here last grid-step
                XH = h_hi + ((size_t)(p_x * 2 + dir) << 16);
                XL = h_lo + ((size_t)(p_x * 2 + dir) << 16);
            }
            const unsigned short* HH = h_hi + ((size_t)((slot * 2 + p_r) * 2 + dir) << 16);
            const unsigned short* HL = h_lo + ((size_t)((slot * 2 + p_r) * 2 + dir) << 16);

            f32x4 acc[2][4];
            #pragma unroll
            for (int mt = 0; mt < 2; ++mt)
                #pragma unroll
                for (int nt = 0; nt < 4; ++nt)
                    acc[mt][nt] = (f32x4){0.f, 0.f, 0.f, 0.f};

            #pragma unroll
            for (int kcl = 0; kcl < 4; ++kcl) {
                int kc = kh * 4 + kcl;
                bf16x8 bxh[4], bxl[4], bhh[4], bhl[4];
                #pragma unroll
                for (int nt = 0; nt < 4; ++nt) {
                    size_t bo = (size_t)(nh * 4 + nt) * 8192 + (size_t)kc * 512 + (size_t)lane * 8;
                    uint4 vh = *(const uint4*)(XH + bo);
                    uint4 vl = *(const uint4*)(XL + bo);
                    if (slot && !(t_eff < lenv[nt])) {
                        vh = make_uint4(0, 0, 0, 0);
                        vl = make_uint4(0, 0, 0, 0);
                    }
                    bxh[nt] = __builtin_bit_cast(bf16x8, vh);
                    bxl[nt] = __builtin_bit_cast(bf16x8, vl);
                    bhh[nt] = *(const bf16x8*)(HH + bo);
                    bhl[nt] = *(const bf16x8*)(HL + bo);
                }
                #pragma unroll
                for (int mt = 0; mt < 2; ++mt) {
                    const char* ab = smem + mt * 16384 + kc * 1024 + lane * 16;
                    bf16x8 aih = *(const bf16x8*)(ab);
                    bf16x8 ail = *(const bf16x8*)(ab + 32768);
                    bf16x8 ahh = *(const bf16x8*)(ab + 65536);
                    bf16x8 ahl = *(const bf16x8*)(ab + 98304);
                    #pragma unroll
                    for (int nt = 0; nt < 4; ++nt) {
                        f32x4 a = acc[mt][nt];
                        a = __builtin_amdgcn_mfma_f32_16x16x32_bf16(aih, bxh[nt], a, 0, 0, 0);
                        a = __builtin_amdgcn_mfma_f32_16x16x32_bf16(aih, bxl[nt], a, 0, 0, 0);
                        a = __builtin_amdgcn_mfma_f32_16x16x32_bf16(ail, bxh[nt], a, 0, 0, 0);
                        a = __builtin_amdgcn_mfma_f32_16x16x32_bf16(ahh, bhh[nt], a, 0, 0, 0);
                        a = __builtin_amdgcn_mfma_f32_16x16x32_bf16(ahh, bhl[nt], a, 0, 0, 0);
                        a = __builtin_amdgcn_mfma_f32_16x16x32_bf16(ahl, bhh[nt], a, 0, 0, 0);
                        acc[mt][nt] = a;
                    }
                }
            }

            unsigned short* HwH = h_hi + ((size_t)((slot * 2 + p_w) * 2 + dir) << 16);
            unsigned short* HwL = h_lo + ((size_t)((slot * 2 + p_w) * 2 + dir) << 16);

            const int crow = (lane >> 4) * 4;
            #pragma unroll
            for (int c = 0; c < 4; ++c) {
                #pragma unroll
                for (int mt = 0; mt < 2; ++mt)
                    #pragma unroll
                    for (int r = 0; r < 4; ++r)
                        exch[(kh * 32 + mt * 16 + crow + r) * 33 + nh * 16 + l15] = acc[mt][c][r];
                __syncthreads();
                if (tid < 256) {
                    float g[4];
                    #pragma unroll
                    for (int q = 0; q < 4; ++q) {
                        int row = q * 8 + cu_u;
                        g[q] = exch[(0 + row) * 33 + cu_b] + exch[(32 + row) * 33 + cu_b]
                             + exch[(64 + row) * 33 + cu_b] + exch[(96 + row) * 33 + cu_b]
                             + bias_c[q];
                    }
                    int gb = (cu_b < 16) ? (c * 16 + cu_b) : (64 + c * 16 + (cu_b - 16));
                    float cv = cst[cu_u * 132 + gb];
                    float iG = 1.f / (1.f + expf(-g[0]));
                    float fG = 1.f / (1.f + expf(-g[1]));
                    float gG = tanhf(g[2]);
                    float oG = 1.f / (1.f + expf(-g[3]));
                    float cn = fG * cv + iG * gG;
                    cst[cu_u * 132 + gb] = cn;
                    float hn = oG * tanhf(cn);
                    unsigned short hh_ = f2bf(hn);
                    unsigned short hl_ = f2bf(hn - bf2f(hh_));
                    int hj = hj0 + cu_u;
                    size_t ho = (((size_t)(gb >> 4) * 16 + (hj >> 5)) * 64
                                 + ((hj >> 3) & 3) * 16 + (gb & 15)) * 8 + (hj & 7);
                    HwH[ho] = hh_;
                    HwL[ho] = hl_;
                    if (slot) {
                        float hm = (t_eff < len_c[c]) ? hn : 0.f;
                        dout[((size_t)gb * 200 + t_eff) * 1024 + dir * 512 + hj] = hm;
                    }
                }
                __syncthreads();
            }
        }
        grid.sync();
    }
}

// ---------------- host ----------------
extern "C" void kernel_launch(void* const* d_in, const int* in_sizes, int n_in,
                              void* d_out, int out_size, void* d_ws, size_t ws_size,
                              hipStream_t stream) {
    const float* x     = (const float*)d_in[0];
    const int*   lens  = (const int*)d_in[1];     // int32 (JAX x64-disabled)
    const float* Wih_f = (const float*)d_in[2];
    const float* Whh_f = (const float*)d_in[3];
    const float* bih_f = (const float*)d_in[4];
    const float* bhh_f = (const float*)d_in[5];
    const float* Wih_b = (const float*)d_in[6];
    const float* Whh_b = (const float*)d_in[7];
    const float* bih_b = (const float*)d_in[8];
    const float* bhh_b = (const float*)d_in[9];
    float* out = (float*)d_out;
    char* ws = (char*)d_ws;
    if (ws_size < 88113152) return;

    unsigned short* xh    = (unsigned short*)(ws);                 // 26,214,400
    unsigned short* xl    = (unsigned short*)(ws + 26214400);      // 26,214,400
    unsigned short* wprep = (unsigned short*)(ws + 52428800);      // 33,554,432
    float*          bsum  = (float*)(ws + 85983232);               //     32,768
    unsigned short* hhi   = (unsigned short*)(ws + 86016000);      //  1,048,576
    unsigned short* hlo   = (unsigned short*)(ws + 87064576);      //  1,048,576

    prep_x<<<6400, 256, 0, stream>>>(x, xh, xl);
    prep_w<<<1024, 256, 0, stream>>>(Wih_f, wprep, 0, 0);
    prep_w<<<1024, 256, 0, stream>>>(Whh_f, wprep, 0, 1);
    prep_w<<<1024, 256, 0, stream>>>(Wih_b, wprep, 1, 0);
    prep_w<<<1024, 256, 0, stream>>>(Whh_b, wprep, 1, 1);
    bsum_k<<<32, 256, 0, stream>>>(bih_f, bhh_f, bih_b, bhh_b, bsum);
    reset_k<<<512, 256, 0, stream>>>((uint4*)hhi);   // zeroes hhi | hlo (contiguous)

    static const int LDS_BYTES = 131072 + 16896 + 4224;  // 152,192
    hipFuncSetAttribute(reinterpret_cast<const void*>(lstm_persist),
                        hipFuncAttributeMaxDynamicSharedMemorySize, LDS_BYTES);

    void* args[] = {(void*)&xh, (void*)&xl, (void*)&wprep, (void*)&bsum,
                    (void*)&hhi, (void*)&hlo, (void*)&lens, (void*)&out};
    hipLaunchCooperativeKernel(reinterpret_cast<void*>(lstm_persist),
                               dim3(256), dim3(512), args, LDS_BYTES, stream);
}

// Round 6
// 4609.475 us; speedup vs baseline: 1.7612x; 1.7612x over previous
//
#include <hip/hip_runtime.h>
#include <hip/hip_bf16.h>
#include <hip/hip_cooperative_groups.h>

typedef __bf16 bf16x8 __attribute__((ext_vector_type(8)));
typedef float f32x4 __attribute__((ext_vector_type(4)));

__device__ __forceinline__ unsigned short f2bf(float f) {
    unsigned int u = __builtin_bit_cast(unsigned int, f);
    u += 0x7FFFu + ((u >> 16) & 1u);
    return (unsigned short)(u >> 16);
}
__device__ __forceinline__ float bf2f(unsigned short s) {
    unsigned int u = ((unsigned int)s) << 16;
    return __builtin_bit_cast(float, u);
}

// ---------------- prep: x -> split bf16 hi/lo in MFMA B-fragment layout ----------------
// layout: [t(200)][nt(8)][kc(16)][lane(64)][e(8)]; batch = nt*16+(lane&15), k = kc*32+(lane>>4)*8+e
__global__ void prep_x(const float* __restrict__ x,
                       unsigned short* __restrict__ xh,
                       unsigned short* __restrict__ xl) {
    int g = blockIdx.x * 256 + threadIdx.x;   // 1,638,400 frags
    if (g >= 1638400) return;
    int lane = g & 63;
    int kc   = (g >> 6) & 15;
    int nt   = (g >> 10) & 7;
    int t    = g >> 13;
    int batch = nt * 16 + (lane & 15);
    int k = kc * 32 + (lane >> 4) * 8;
    const float* s = x + ((size_t)batch * 200 + t) * 512 + k;
    float4 v0 = *(const float4*)s;
    float4 v1 = *(const float4*)(s + 4);
    float vv[8] = {v0.x, v0.y, v0.z, v0.w, v1.x, v1.y, v1.z, v1.w};
    unsigned int ph[4], pl[4];
    #pragma unroll
    for (int j = 0; j < 4; ++j) {
        float a = vv[2*j], b = vv[2*j+1];
        unsigned short ha = f2bf(a), hb = f2bf(b);
        unsigned short la = f2bf(a - bf2f(ha)), lb = f2bf(b - bf2f(hb));
        ph[j] = (unsigned)ha | ((unsigned)hb << 16);
        pl[j] = (unsigned)la | ((unsigned)lb << 16);
    }
    ((uint4*)xh)[g] = make_uint4(ph[0], ph[1], ph[2], ph[3]);
    ((uint4*)xl)[g] = make_uint4(pl[0], pl[1], pl[2], pl[3]);
}

// ---------------- prep: weights -> per-CU LDS image blocks ----------------
// dst block per (wu = dir*2+layer, cu 0..63): 8192 frags of 16B (131072 B):
//   frag idx within block = mat*2048 + mt*1024 + kc*64 + lane
//   mat: 0=ihH 1=ihL 2=hhH 3=hhL; within frag: row r=lane&15, k=kc*32+(lane>>4)*8+e
//   global gate row = (2*mt + (r>>3))*512 + cu*8 + (r&7)
__global__ void prep_w(const float* __restrict__ W,     // [2][2048][512] f32
                       unsigned short* __restrict__ wprep,
                       int dir, int isHH) {
    int g = blockIdx.x * 256 + threadIdx.x;   // 262,144
    if (g >= 262144) return;
    int lane = g & 63;
    int kc   = (g >> 6) & 15;
    int mt   = (g >> 10) & 1;
    int cu   = (g >> 11) & 63;
    int l    = g >> 17;
    int r = lane & 15;
    int grow = (2 * mt + (r >> 3)) * 512 + cu * 8 + (r & 7);
    int k = kc * 32 + (lane >> 4) * 8;
    const float* s = W + ((size_t)l * 2048 + grow) * 512 + k;
    float4 v0 = *(const float4*)s;
    float4 v1 = *(const float4*)(s + 4);
    float vv[8] = {v0.x, v0.y, v0.z, v0.w, v1.x, v1.y, v1.z, v1.w};
    unsigned int ph[4], pl[4];
    #pragma unroll
    for (int j = 0; j < 4; ++j) {
        float a = vv[2*j], b = vv[2*j+1];
        unsigned short ha = f2bf(a), hb = f2bf(b);
        unsigned short la = f2bf(a - bf2f(ha)), lb = f2bf(b - bf2f(hb));
        ph[j] = (unsigned)ha | ((unsigned)hb << 16);
        pl[j] = (unsigned)la | ((unsigned)lb << 16);
    }
    size_t blk = ((size_t)(dir * 2 + l) * 64 + cu) * 8192;
    size_t fH = blk + (size_t)((isHH * 2 + 0) * 2048 + mt * 1024 + kc * 64 + lane);
    size_t fL = blk + (size_t)((isHH * 2 + 1) * 2048 + mt * 1024 + kc * 64 + lane);
    ((uint4*)wprep)[fH] = make_uint4(ph[0], ph[1], ph[2], ph[3]);
    ((uint4*)wprep)[fL] = make_uint4(pl[0], pl[1], pl[2], pl[3]);
}

__global__ void bsum_k(const float* __restrict__ bih_f, const float* __restrict__ bhh_f,
                       const float* __restrict__ bih_b, const float* __restrict__ bhh_b,
                       float* __restrict__ bsum) {
    int i = blockIdx.x * 256 + threadIdx.x;   // 8192 = [dir][l][2048]
    if (i < 8192) {
        int dir = i >> 12, rem = i & 4095;
        const float* bi = dir ? bih_b : bih_f;
        const float* bh = dir ? bhh_b : bhh_f;
        bsum[i] = bi[rem] + bh[rem];
    }
}

__global__ void reset_k(uint4* __restrict__ p) {  // zero h_hi | h_lo | ctr (3,145,984 B)
    int g = blockIdx.x * 256 + threadIdx.x;
    if (g < 196624) p[g] = make_uint4(0, 0, 0, 0);
}

__device__ __forceinline__ void spin_wait(unsigned* c, unsigned target) {
    while (__hip_atomic_load(c, __ATOMIC_RELAXED, __HIP_MEMORY_SCOPE_AGENT) < target)
        __builtin_amdgcn_s_sleep(8);
}

// ---------------- persistent cooperative LSTM ----------------
// 256 WGs (1/CU) x 512 threads. unit = xcd>>1 (slot=unit>>1, dir=unit&1);
// CU owns 8 hidden units (hj0 = cu8*8): gate rows {q*512+hj0..+7}, all 128 batches.
// Waves: kh = wave&3 (K-split, kc = kh*4+kcl), nh = wave>>2 (batch half).
// Weights stay in LDS for all 200 steps; c-state in LDS; h is triple-buffered
// (parity = t mod 3) in global, B-frag layout. Per-unit flag barriers replace
// grid.sync: producers release-add a 64-WG arrival counter; consumers spin.
__global__ void __launch_bounds__(512)
lstm_persist(const unsigned short* __restrict__ xh,
             const unsigned short* __restrict__ xl,
             const unsigned short* __restrict__ wprep,
             const float*          __restrict__ bsum,
             unsigned short*       __restrict__ h_hi,   // [(slot*3+parity)*2+dir] x 65536
             unsigned short*       __restrict__ h_lo,
             const int*            __restrict__ lens,
             float*                __restrict__ dout,   // [128][200][1024]
             unsigned*             __restrict__ ctr)    // 4 counters, 64B-strided
{
    extern __shared__ char smem[];
    float* exch = (float*)(smem + 131072);            // [kh4][row32][33] = 16,896 B
    float* cst  = (float*)(smem + 131072 + 16896);    // [u8][132] = 4,224 B

    const int bid  = blockIdx.x;
    const int xcd  = bid & 7;
    const int unit = xcd >> 1;
    const int slot = unit >> 1, dir = unit & 1;
    const int cu8  = ((xcd & 1) << 5) | (bid >> 3);   // 0..63
    const int hj0  = cu8 * 8;
    const int tid  = threadIdx.x;
    const int lane = tid & 63, wv = tid >> 6;
    const int kh = wv & 3, nh = wv >> 2;
    const int l15 = lane & 15;
    const int wsel = dir * 2 + slot;                  // dir-major, matches prep_w/bsum

    unsigned* own_c = ctr + unit * 16;                            // slot-major unit id
    unsigned* sib_c = ctr + (slot ? dir : (2 + dir)) * 16;        // the other slot, same dir

    // ---- stage weights into LDS (one-time) ----
    {
        const uint4* src = (const uint4*)wprep + ((size_t)(wsel * 64 + cu8) * 8192);
        uint4* dst = (uint4*)smem;
        #pragma unroll
        for (int i = 0; i < 16; ++i) dst[tid + i * 512] = src[tid + i * 512];
    }
    for (int i = tid; i < 8 * 132; i += 512) cst[i] = 0.f;
    __syncthreads();

    // ---- loop invariants ----
    int lenv[4];
    #pragma unroll
    for (int nt = 0; nt < 4; ++nt) lenv[nt] = lens[(nh * 4 + nt) * 16 + l15];

    const int cu_u = tid >> 5, cu_b = tid & 31;       // cell role (tid < 256)
    float bias_c[4];
    int   len_c[4];
    if (tid < 256) {
        #pragma unroll
        for (int q = 0; q < 4; ++q) bias_c[q] = bsum[wsel * 2048 + q * 512 + hj0 + cu_u];
        #pragma unroll
        for (int c = 0; c < 4; ++c) {
            int gb = (cu_b < 16) ? (c * 16 + cu_b) : (64 + c * 16 + (cu_b - 16));
            len_c[c] = lens[gb];
        }
    }

    for (int tau = 0; tau <= 200; ++tau) {
        // ---- wait for dependencies (thread 0 only) ----
        if (tid == 0) {
            unsigned tgt = 64u * (unsigned)tau;
            spin_wait(own_c, tgt);                    // own unit finished tau-1
            if (slot == 1) spin_wait(sib_c, tgt);     // data dep: slot0 finished tau-1
            else if (tau >= 2) spin_wait(sib_c, 64u * (unsigned)(tau - 1));  // WAR (triple-buf slack)
            __threadfence();                          // acquire: invalidate stale L2
        }
        __syncthreads();

        int t = slot ? (tau - 1) : tau;
        if (t >= 0 && t <= 199) {
            int t_eff = dir ? (199 - t) : t;
            int p_w = t % 3;                          // write parity
            int p_r = (t + 2) % 3;                    // read parity (t-1 mod 3)

            const unsigned short* XH;
            const unsigned short* XL;
            if (slot == 0) {
                XH = xh + (size_t)t_eff * 65536;
                XL = xl + (size_t)t_eff * 65536;
            } else {
                int p_x = t % 3;                      // layer0 wrote h_t at parity t%3
                XH = h_hi + ((size_t)(p_x * 2 + dir) << 16);
                XL = h_lo + ((size_t)(p_x * 2 + dir) << 16);
            }
            const unsigned short* HH = h_hi + ((size_t)((slot * 3 + p_r) * 2 + dir) << 16);
            const unsigned short* HL = h_lo + ((size_t)((slot * 3 + p_r) * 2 + dir) << 16);

            f32x4 acc[2][4];
            #pragma unroll
            for (int mt = 0; mt < 2; ++mt)
                #pragma unroll
                for (int nt = 0; nt < 4; ++nt)
                    acc[mt][nt] = (f32x4){0.f, 0.f, 0.f, 0.f};

            #pragma unroll
            for (int kcl = 0; kcl < 4; ++kcl) {
                int kc = kh * 4 + kcl;
                bf16x8 bxh[4], bxl[4], bhh[4], bhl[4];
                #pragma unroll
                for (int nt = 0; nt < 4; ++nt) {
                    size_t bo = (size_t)(nh * 4 + nt) * 8192 + (size_t)kc * 512 + (size_t)lane * 8;
                    uint4 vh = *(const uint4*)(XH + bo);
                    uint4 vl = *(const uint4*)(XL + bo);
                    if (slot && !(t_eff < lenv[nt])) {
                        vh = make_uint4(0, 0, 0, 0);
                        vl = make_uint4(0, 0, 0, 0);
                    }
                    bxh[nt] = __builtin_bit_cast(bf16x8, vh);
                    bxl[nt] = __builtin_bit_cast(bf16x8, vl);
                    bhh[nt] = *(const bf16x8*)(HH + bo);
                    bhl[nt] = *(const bf16x8*)(HL + bo);
                }
                #pragma unroll
                for (int mt = 0; mt < 2; ++mt) {
                    const char* ab = smem + mt * 16384 + kc * 1024 + lane * 16;
                    bf16x8 aih = *(const bf16x8*)(ab);
                    bf16x8 ail = *(const bf16x8*)(ab + 32768);
                    bf16x8 ahh = *(const bf16x8*)(ab + 65536);
                    bf16x8 ahl = *(const bf16x8*)(ab + 98304);
                    #pragma unroll
                    for (int nt = 0; nt < 4; ++nt) {
                        f32x4 a = acc[mt][nt];
                        a = __builtin_amdgcn_mfma_f32_16x16x32_bf16(aih, bxh[nt], a, 0, 0, 0);
                        a = __builtin_amdgcn_mfma_f32_16x16x32_bf16(aih, bxl[nt], a, 0, 0, 0);
                        a = __builtin_amdgcn_mfma_f32_16x16x32_bf16(ail, bxh[nt], a, 0, 0, 0);
                        a = __builtin_amdgcn_mfma_f32_16x16x32_bf16(ahh, bhh[nt], a, 0, 0, 0);
                        a = __builtin_amdgcn_mfma_f32_16x16x32_bf16(ahh, bhl[nt], a, 0, 0, 0);
                        a = __builtin_amdgcn_mfma_f32_16x16x32_bf16(ahl, bhh[nt], a, 0, 0, 0);
                        acc[mt][nt] = a;
                    }
                }
            }

            unsigned short* HwH = h_hi + ((size_t)((slot * 3 + p_w) * 2 + dir) << 16);
            unsigned short* HwL = h_lo + ((size_t)((slot * 3 + p_w) * 2 + dir) << 16);

            const int crow = (lane >> 4) * 4;
            #pragma unroll
            for (int c = 0; c < 4; ++c) {
                #pragma unroll
                for (int mt = 0; mt < 2; ++mt)
                    #pragma unroll
                    for (int r = 0; r < 4; ++r)
                        exch[(kh * 32 + mt * 16 + crow + r) * 33 + nh * 16 + l15] = acc[mt][c][r];
                __syncthreads();
                if (tid < 256) {
                    float g[4];
                    #pragma unroll
                    for (int q = 0; q < 4; ++q) {
                        int row = q * 8 + cu_u;
                        g[q] = exch[(0 + row) * 33 + cu_b] + exch[(32 + row) * 33 + cu_b]
                             + exch[(64 + row) * 33 + cu_b] + exch[(96 + row) * 33 + cu_b]
                             + bias_c[q];
                    }
                    int gb = (cu_b < 16) ? (c * 16 + cu_b) : (64 + c * 16 + (cu_b - 16));
                    float cv = cst[cu_u * 132 + gb];
                    float iG = 1.f / (1.f + expf(-g[0]));
                    float fG = 1.f / (1.f + expf(-g[1]));
                    float gG = tanhf(g[2]);
                    float oG = 1.f / (1.f + expf(-g[3]));
                    float cn = fG * cv + iG * gG;
                    cst[cu_u * 132 + gb] = cn;
                    float hn = oG * tanhf(cn);
                    unsigned short hh_ = f2bf(hn);
                    unsigned short hl_ = f2bf(hn - bf2f(hh_));
                    int hj = hj0 + cu_u;
                    size_t ho = (((size_t)(gb >> 4) * 16 + (hj >> 5)) * 64
                                 + ((hj >> 3) & 3) * 16 + (gb & 15)) * 8 + (hj & 7);
                    HwH[ho] = hh_;
                    HwL[ho] = hl_;
                    if (slot) {
                        float hm = (t_eff < len_c[c]) ? hn : 0.f;
                        dout[((size_t)gb * 200 + t_eff) * 1024 + dir * 512 + hj] = hm;
                    }
                }
                __syncthreads();   // also drains h stores before the release-add below
            }
        }

        // ---- signal completion of iteration tau (h writes visible via release) ----
        if (tid == 0)
            __hip_atomic_fetch_add(own_c, 1u, __ATOMIC_RELEASE, __HIP_MEMORY_SCOPE_AGENT);
    }
}

// ---------------- host ----------------
extern "C" void kernel_launch(void* const* d_in, const int* in_sizes, int n_in,
                              void* d_out, int out_size, void* d_ws, size_t ws_size,
                              hipStream_t stream) {
    const float* x     = (const float*)d_in[0];
    const int*   lens  = (const int*)d_in[1];     // int32 (JAX x64-disabled)
    const float* Wih_f = (const float*)d_in[2];
    const float* Whh_f = (const float*)d_in[3];
    const float* bih_f = (const float*)d_in[4];
    const float* bhh_f = (const float*)d_in[5];
    const float* Wih_b = (const float*)d_in[6];
    const float* Whh_b = (const float*)d_in[7];
    const float* bih_b = (const float*)d_in[8];
    const float* bhh_b = (const float*)d_in[9];
    float* out = (float*)d_out;
    char* ws = (char*)d_ws;
    if (ws_size < 89161984) return;

    unsigned short* xh    = (unsigned short*)(ws);                 // 26,214,400
    unsigned short* xl    = (unsigned short*)(ws + 26214400);      // 26,214,400
    unsigned short* wprep = (unsigned short*)(ws + 52428800);      // 33,554,432
    float*          bsum  = (float*)(ws + 85983232);               //     32,768
    unsigned short* hhi   = (unsigned short*)(ws + 86016000);      //  1,572,864
    unsigned short* hlo   = (unsigned short*)(ws + 87588864);      //  1,572,864
    unsigned*       ctr   = (unsigned*)(ws + 89161728);            //        256

    prep_x<<<6400, 256, 0, stream>>>(x, xh, xl);
    prep_w<<<1024, 256, 0, stream>>>(Wih_f, wprep, 0, 0);
    prep_w<<<1024, 256, 0, stream>>>(Whh_f, wprep, 0, 1);
    prep_w<<<1024, 256, 0, stream>>>(Wih_b, wprep, 1, 0);
    prep_w<<<1024, 256, 0, stream>>>(Whh_b, wprep, 1, 1);
    bsum_k<<<32, 256, 0, stream>>>(bih_f, bhh_f, bih_b, bhh_b, bsum);
    reset_k<<<769, 256, 0, stream>>>((uint4*)hhi);   // zeroes hhi | hlo | ctr (contiguous)

    static const int LDS_BYTES = 131072 + 16896 + 4224;  // 152,192
    hipFuncSetAttribute(reinterpret_cast<const void*>(lstm_persist),
                        hipFuncAttributeMaxDynamicSharedMemorySize, LDS_BYTES);

    void* args[] = {(void*)&xh, (void*)&xl, (void*)&wprep, (void*)&bsum,
                    (void*)&hhi, (void*)&hlo, (void*)&lens, (void*)&out, (void*)&ctr};
    hipLaunchCooperativeKernel(reinterpret_cast<void*>(lstm_persist),
                               dim3(256), dim3(512), args, LDS_BYTES, stream);
}

// Round 7
// 3108.294 us; speedup vs baseline: 2.6118x; 1.4830x over previous
//
#include <hip/hip_runtime.h>
#include <hip/hip_bf16.h>

typedef __bf16 bf16x8 __attribute__((ext_vector_type(8)));
typedef float f32x4 __attribute__((ext_vector_type(4)));

__device__ __forceinline__ unsigned short f2bf(float f) {
    unsigned int u = __builtin_bit_cast(unsigned int, f);
    u += 0x7FFFu + ((u >> 16) & 1u);
    return (unsigned short)(u >> 16);
}
__device__ __forceinline__ float bf2f(unsigned short s) {
    unsigned int u = ((unsigned int)s) << 16;
    return __builtin_bit_cast(float, u);
}

// Coherent (L1/L2-bypass, L3-served) 16B load: issue only; caller batches a
// single s_waitcnt vmcnt(0) + sched_barrier afterwards (guide §5.5 rule 18).
__device__ __forceinline__ void ldg_c(uint4& d, const void* p) {
    asm volatile("global_load_dwordx4 %0, %1, off sc0 sc1" : "=v"(d) : "v"(p));
}
__device__ __forceinline__ void vm_drain() {
    asm volatile("s_waitcnt vmcnt(0)" ::: "memory");
    __builtin_amdgcn_sched_barrier(0);
}
// Coherent write-through 16-bit store.
__device__ __forceinline__ void stg_c16(void* p, unsigned short v) {
    asm volatile("global_store_short %0, %1, off sc0 sc1" :: "v"(p), "v"(v) : "memory");
}

// ---------------- prep: x -> split bf16 hi/lo in MFMA B-fragment layout ----------------
// layout: [t(200)][nt(8)][kc(16)][lane(64)][e(8)]; batch = nt*16+(lane&15), k = kc*32+(lane>>4)*8+e
__global__ void prep_x(const float* __restrict__ x,
                       unsigned short* __restrict__ xh,
                       unsigned short* __restrict__ xl) {
    int g = blockIdx.x * 256 + threadIdx.x;   // 1,638,400 frags
    if (g >= 1638400) return;
    int lane = g & 63;
    int kc   = (g >> 6) & 15;
    int nt   = (g >> 10) & 7;
    int t    = g >> 13;
    int batch = nt * 16 + (lane & 15);
    int k = kc * 32 + (lane >> 4) * 8;
    const float* s = x + ((size_t)batch * 200 + t) * 512 + k;
    float4 v0 = *(const float4*)s;
    float4 v1 = *(const float4*)(s + 4);
    float vv[8] = {v0.x, v0.y, v0.z, v0.w, v1.x, v1.y, v1.z, v1.w};
    unsigned int ph[4], pl[4];
    #pragma unroll
    for (int j = 0; j < 4; ++j) {
        float a = vv[2*j], b = vv[2*j+1];
        unsigned short ha = f2bf(a), hb = f2bf(b);
        unsigned short la = f2bf(a - bf2f(ha)), lb = f2bf(b - bf2f(hb));
        ph[j] = (unsigned)ha | ((unsigned)hb << 16);
        pl[j] = (unsigned)la | ((unsigned)lb << 16);
    }
    ((uint4*)xh)[g] = make_uint4(ph[0], ph[1], ph[2], ph[3]);
    ((uint4*)xl)[g] = make_uint4(pl[0], pl[1], pl[2], pl[3]);
}

// ---------------- prep: weights -> per-CU LDS image blocks ----------------
// dst block per (wu = dir*2+layer, cu 0..63): 8192 frags of 16B (131072 B):
//   frag idx within block = mat*2048 + mt*1024 + kc*64 + lane
//   mat: 0=ihH 1=ihL 2=hhH 3=hhL; within frag: row r=lane&15, k=kc*32+(lane>>4)*8+e
//   global gate row = (2*mt + (r>>3))*512 + cu*8 + (r&7)
__global__ void prep_w(const float* __restrict__ W,     // [2][2048][512] f32
                       unsigned short* __restrict__ wprep,
                       int dir, int isHH) {
    int g = blockIdx.x * 256 + threadIdx.x;   // 262,144
    if (g >= 262144) return;
    int lane = g & 63;
    int kc   = (g >> 6) & 15;
    int mt   = (g >> 10) & 1;
    int cu   = (g >> 11) & 63;
    int l    = g >> 17;
    int r = lane & 15;
    int grow = (2 * mt + (r >> 3)) * 512 + cu * 8 + (r & 7);
    int k = kc * 32 + (lane >> 4) * 8;
    const float* s = W + ((size_t)l * 2048 + grow) * 512 + k;
    float4 v0 = *(const float4*)s;
    float4 v1 = *(const float4*)(s + 4);
    float vv[8] = {v0.x, v0.y, v0.z, v0.w, v1.x, v1.y, v1.z, v1.w};
    unsigned int ph[4], pl[4];
    #pragma unroll
    for (int j = 0; j < 4; ++j) {
        float a = vv[2*j], b = vv[2*j+1];
        unsigned short ha = f2bf(a), hb = f2bf(b);
        unsigned short la = f2bf(a - bf2f(ha)), lb = f2bf(b - bf2f(hb));
        ph[j] = (unsigned)ha | ((unsigned)hb << 16);
        pl[j] = (unsigned)la | ((unsigned)lb << 16);
    }
    size_t blk = ((size_t)(dir * 2 + l) * 64 + cu) * 8192;
    size_t fH = blk + (size_t)((isHH * 2 + 0) * 2048 + mt * 1024 + kc * 64 + lane);
    size_t fL = blk + (size_t)((isHH * 2 + 1) * 2048 + mt * 1024 + kc * 64 + lane);
    ((uint4*)wprep)[fH] = make_uint4(ph[0], ph[1], ph[2], ph[3]);
    ((uint4*)wprep)[fL] = make_uint4(pl[0], pl[1], pl[2], pl[3]);
}

__global__ void bsum_k(const float* __restrict__ bih_f, const float* __restrict__ bhh_f,
                       const float* __restrict__ bih_b, const float* __restrict__ bhh_b,
                       float* __restrict__ bsum) {
    int i = blockIdx.x * 256 + threadIdx.x;   // 8192 = [dir][l][2048]
    if (i < 8192) {
        int dir = i >> 12, rem = i & 4095;
        const float* bi = dir ? bih_b : bih_f;
        const float* bh = dir ? bhh_b : bhh_f;
        bsum[i] = bi[rem] + bh[rem];
    }
}

__global__ void reset_k(uint4* __restrict__ p) {  // zero h_hi | h_lo | ctr (3,145,984 B)
    int g = blockIdx.x * 256 + threadIdx.x;
    if (g < 196624) p[g] = make_uint4(0, 0, 0, 0);
}

__device__ __forceinline__ void spin_wait(unsigned* c, unsigned target) {
    while (__hip_atomic_load(c, __ATOMIC_RELAXED, __HIP_MEMORY_SCOPE_AGENT) < target)
        __builtin_amdgcn_s_sleep(1);
}

// ---------------- persistent LSTM (cooperative launch, flag barriers) ----------------
// 256 WGs (1/CU) x 512 threads. unit = xcd>>1 (slot=unit>>1, dir=unit&1);
// CU owns 8 hidden units (hj0 = cu8*8): gate rows {q*512+hj0..+7}, all 128 batches.
// Waves: kh = wave&3 (K-split, kc = kh*4+kcl), nh = wave>>2 (batch half).
// Weights LDS-resident all 200 steps; c-state in LDS; h triple-buffered in global
// (parity = t mod 3), accessed ONLY via sc0/sc1-coherent loads/stores (no cache
// fences). slot0's ih-MFMAs run before the spin (off the serial chain).
__global__ void __launch_bounds__(512)
lstm_persist(const unsigned short* __restrict__ xh,
             const unsigned short* __restrict__ xl,
             const unsigned short* __restrict__ wprep,
             const float*          __restrict__ bsum,
             unsigned short*       __restrict__ h_hi,   // [(slot*3+parity)*2+dir] x 65536
             unsigned short*       __restrict__ h_lo,
             const int*            __restrict__ lens,
             float*                __restrict__ dout,   // [128][200][1024]
             unsigned*             __restrict__ ctr)    // 4 counters, 64B-strided
{
    extern __shared__ char smem[];
    float* exch = (float*)(smem + 131072);            // [kh4][row32][33] = 16,896 B
    float* cst  = (float*)(smem + 131072 + 16896);    // [u8][132] = 4,224 B

    const int bid  = blockIdx.x;
    const int xcd  = bid & 7;
    const int unit = xcd >> 1;
    const int slot = unit >> 1, dir = unit & 1;
    const int cu8  = ((xcd & 1) << 5) | (bid >> 3);   // 0..63
    const int hj0  = cu8 * 8;
    const int tid  = threadIdx.x;
    const int lane = tid & 63, wv = tid >> 6;
    const int kh = wv & 3, nh = wv >> 2;
    const int l15 = lane & 15;
    const int wsel = dir * 2 + slot;                  // dir-major, matches prep_w/bsum

    unsigned* own_c = ctr + unit * 16;                            // slot-major unit id
    unsigned* sib_c = ctr + (slot ? dir : (2 + dir)) * 16;        // the other slot, same dir

    // ---- stage weights into LDS (one-time) ----
    {
        const uint4* src = (const uint4*)wprep + ((size_t)(wsel * 64 + cu8) * 8192);
        uint4* dst = (uint4*)smem;
        #pragma unroll
        for (int i = 0; i < 16; ++i) dst[tid + i * 512] = src[tid + i * 512];
    }
    for (int i = tid; i < 8 * 132; i += 512) cst[i] = 0.f;
    __syncthreads();

    // ---- loop invariants ----
    int lenv[4];
    #pragma unroll
    for (int nt = 0; nt < 4; ++nt) lenv[nt] = lens[(nh * 4 + nt) * 16 + l15];

    const int cu_u = tid >> 5, cu_b = tid & 31;       // cell role (tid < 256)
    float bias_c[4];
    int   len_c[4];
    if (tid < 256) {
        #pragma unroll
        for (int q = 0; q < 4; ++q) bias_c[q] = bsum[wsel * 2048 + q * 512 + hj0 + cu_u];
        #pragma unroll
        for (int c = 0; c < 4; ++c) {
            int gb = (cu_b < 16) ? (c * 16 + cu_b) : (64 + c * 16 + (cu_b - 16));
            len_c[c] = lens[gb];
        }
    }

    const size_t lofs = (size_t)lane * 8;

    for (int tau = 0; tau <= 200; ++tau) {
        const int t = slot ? (tau - 1) : tau;
        const bool active = (t >= 0 && t <= 199);
        int t_eff = 0, p_w = 0, p_r = 0;
        if (active) { t_eff = dir ? (199 - t) : t; p_w = t % 3; p_r = (t + 2) % 3; }

        f32x4 acc[2][4];
        #pragma unroll
        for (int mt = 0; mt < 2; ++mt)
            #pragma unroll
            for (int nt = 0; nt < 4; ++nt)
                acc[mt][nt] = (f32x4){0.f, 0.f, 0.f, 0.f};

        // ---- Phase 1 (slot0 only): ih * x_t — independent of the recurrence ----
        if (slot == 0 && active) {
            const unsigned short* XH = xh + (size_t)t_eff * 65536;
            const unsigned short* XL = xl + (size_t)t_eff * 65536;
            #pragma unroll
            for (int kcl = 0; kcl < 4; ++kcl) {
                int kc = kh * 4 + kcl;
                bf16x8 bxh[4], bxl[4];
                #pragma unroll
                for (int nt = 0; nt < 4; ++nt) {
                    size_t bo = (size_t)(nh * 4 + nt) * 8192 + (size_t)kc * 512 + lofs;
                    bxh[nt] = *(const bf16x8*)(XH + bo);
                    bxl[nt] = *(const bf16x8*)(XL + bo);
                }
                #pragma unroll
                for (int mt = 0; mt < 2; ++mt) {
                    const char* ab = smem + mt * 16384 + kc * 1024 + lane * 16;
                    bf16x8 aih = *(const bf16x8*)(ab);
                    bf16x8 ail = *(const bf16x8*)(ab + 32768);
                    #pragma unroll
                    for (int nt = 0; nt < 4; ++nt) {
                        f32x4 a = acc[mt][nt];
                        a = __builtin_amdgcn_mfma_f32_16x16x32_bf16(aih, bxh[nt], a, 0, 0, 0);
                        a = __builtin_amdgcn_mfma_f32_16x16x32_bf16(aih, bxl[nt], a, 0, 0, 0);
                        a = __builtin_amdgcn_mfma_f32_16x16x32_bf16(ail, bxh[nt], a, 0, 0, 0);
                        acc[mt][nt] = a;
                    }
                }
            }
        }

        // ---- wait for dependencies (thread 0 spins; no cache fences needed:
        //      all cross-CU data moves via sc0/sc1-coherent accesses) ----
        if (tid == 0) {
            unsigned tgt = 64u * (unsigned)tau;
            spin_wait(own_c, tgt);                    // own unit finished tau-1
            if (slot == 1) spin_wait(sib_c, tgt);     // data dep: slot0 finished tau-1
            else if (tau >= 2) spin_wait(sib_c, 64u * (unsigned)(tau - 1));  // WAR slack
        }
        __syncthreads();

        if (active) {
            const unsigned short* HH = h_hi + ((size_t)((slot * 3 + p_r) * 2 + dir) << 16);
            const unsigned short* HL = h_lo + ((size_t)((slot * 3 + p_r) * 2 + dir) << 16);

            // ---- Phase 2: recurrent terms (and, for slot1, the layer0-h input) ----
            if (slot == 0) {
                #pragma unroll
                for (int kcl = 0; kcl < 4; ++kcl) {
                    int kc = kh * 4 + kcl;
                    uint4 vhh[4], vhl[4];
                    #pragma unroll
                    for (int nt = 0; nt < 4; ++nt) {
                        size_t bo = (size_t)(nh * 4 + nt) * 8192 + (size_t)kc * 512 + lofs;
                        ldg_c(vhh[nt], HH + bo);
                        ldg_c(vhl[nt], HL + bo);
                    }
                    vm_drain();
                    #pragma unroll
                    for (int mt = 0; mt < 2; ++mt) {
                        const char* ab = smem + mt * 16384 + kc * 1024 + lane * 16;
                        bf16x8 ahh = *(const bf16x8*)(ab + 65536);
                        bf16x8 ahl = *(const bf16x8*)(ab + 98304);
                        #pragma unroll
                        for (int nt = 0; nt < 4; ++nt) {
                            bf16x8 bh = __builtin_bit_cast(bf16x8, vhh[nt]);
                            bf16x8 bl = __builtin_bit_cast(bf16x8, vhl[nt]);
                            f32x4 a = acc[mt][nt];
                            a = __builtin_amdgcn_mfma_f32_16x16x32_bf16(ahh, bh, a, 0, 0, 0);
                            a = __builtin_amdgcn_mfma_f32_16x16x32_bf16(ahh, bl, a, 0, 0, 0);
                            a = __builtin_amdgcn_mfma_f32_16x16x32_bf16(ahl, bh, a, 0, 0, 0);
                            acc[mt][nt] = a;
                        }
                    }
                }
            } else {
                int p_x = t % 3;                      // layer0 wrote h_t at parity t%3
                const unsigned short* XHc = h_hi + ((size_t)(p_x * 2 + dir) << 16);
                const unsigned short* XLc = h_lo + ((size_t)(p_x * 2 + dir) << 16);
                #pragma unroll
                for (int kcl = 0; kcl < 4; ++kcl) {
                    int kc = kh * 4 + kcl;
                    uint4 vxh[4], vxl[4], vhh[4], vhl[4];
                    #pragma unroll
                    for (int nt = 0; nt < 4; ++nt) {
                        size_t bo = (size_t)(nh * 4 + nt) * 8192 + (size_t)kc * 512 + lofs;
                        ldg_c(vxh[nt], XHc + bo);
                        ldg_c(vxl[nt], XLc + bo);
                        ldg_c(vhh[nt], HH + bo);
                        ldg_c(vhl[nt], HL + bo);
                    }
                    vm_drain();
                    #pragma unroll
                    for (int nt = 0; nt < 4; ++nt)
                        if (!(t_eff < lenv[nt])) {
                            vxh[nt] = make_uint4(0, 0, 0, 0);
                            vxl[nt] = make_uint4(0, 0, 0, 0);
                        }
                    #pragma unroll
                    for (int mt = 0; mt < 2; ++mt) {
                        const char* ab = smem + mt * 16384 + kc * 1024 + lane * 16;
                        bf16x8 aih = *(const bf16x8*)(ab);
                        bf16x8 ail = *(const bf16x8*)(ab + 32768);
                        bf16x8 ahh = *(const bf16x8*)(ab + 65536);
                        bf16x8 ahl = *(const bf16x8*)(ab + 98304);
                        #pragma unroll
                        for (int nt = 0; nt < 4; ++nt) {
                            bf16x8 xhv = __builtin_bit_cast(bf16x8, vxh[nt]);
                            bf16x8 xlv = __builtin_bit_cast(bf16x8, vxl[nt]);
                            bf16x8 bh  = __builtin_bit_cast(bf16x8, vhh[nt]);
                            bf16x8 bl  = __builtin_bit_cast(bf16x8, vhl[nt]);
                            f32x4 a = acc[mt][nt];
                            a = __builtin_amdgcn_mfma_f32_16x16x32_bf16(aih, xhv, a, 0, 0, 0);
                            a = __builtin_amdgcn_mfma_f32_16x16x32_bf16(aih, xlv, a, 0, 0, 0);
                            a = __builtin_amdgcn_mfma_f32_16x16x32_bf16(ail, xhv, a, 0, 0, 0);
                            a = __builtin_amdgcn_mfma_f32_16x16x32_bf16(ahh, bh,  a, 0, 0, 0);
                            a = __builtin_amdgcn_mfma_f32_16x16x32_bf16(ahh, bl,  a, 0, 0, 0);
                            a = __builtin_amdgcn_mfma_f32_16x16x32_bf16(ahl, bh,  a, 0, 0, 0);
                            acc[mt][nt] = a;
                        }
                    }
                }
            }

            unsigned short* HwH = h_hi + ((size_t)((slot * 3 + p_w) * 2 + dir) << 16);
            unsigned short* HwL = h_lo + ((size_t)((slot * 3 + p_w) * 2 + dir) << 16);

            const int crow = (lane >> 4) * 4;
            #pragma unroll
            for (int c = 0; c < 4; ++c) {
                #pragma unroll
                for (int mt = 0; mt < 2; ++mt)
                    #pragma unroll
                    for (int r = 0; r < 4; ++r) {
                        int rr = mt * 16 + crow + r;
                        exch[(kh * 32 + rr) * 33 + nh * 16 + l15] = acc[mt][c][r];
                    }
                __syncthreads();
                if (tid < 256) {
                    float g[4];
                    #pragma unroll
                    for (int q = 0; q < 4; ++q) {
                        int row = q * 8 + cu_u;
                        g[q] = exch[(0 + row) * 33 + cu_b] + exch[(32 + row) * 33 + cu_b]
                             + exch[(64 + row) * 33 + cu_b] + exch[(96 + row) * 33 + cu_b]
                             + bias_c[q];
                    }
                    int gb = (cu_b < 16) ? (c * 16 + cu_b) : (64 + c * 16 + (cu_b - 16));
                    float cv = cst[cu_u * 132 + gb];
                    float iG = 1.f / (1.f + expf(-g[0]));
                    float fG = 1.f / (1.f + expf(-g[1]));
                    float gG = tanhf(g[2]);
                    float oG = 1.f / (1.f + expf(-g[3]));
                    float cn = fG * cv + iG * gG;
                    cst[cu_u * 132 + gb] = cn;
                    float hn = oG * tanhf(cn);
                    unsigned short hh_ = f2bf(hn);
                    unsigned short hl_ = f2bf(hn - bf2f(hh_));
                    int hj = hj0 + cu_u;
                    size_t ho = (((size_t)(gb >> 4) * 16 + (hj >> 5)) * 64
                                 + ((hj >> 3) & 3) * 16 + (gb & 15)) * 8 + (hj & 7);
                    stg_c16(HwH + ho, hh_);
                    stg_c16(HwL + ho, hl_);
                    if (slot) {
                        float hm = (t_eff < len_c[c]) ? hn : 0.f;
                        dout[((size_t)gb * 200 + t_eff) * 1024 + dir * 512 + hj] = hm;
                    }
                }
                __syncthreads();
            }
            // drain the coherent h stores (asm stores are invisible to the
            // compiler's barrier waitcnt) before signaling completion
            if (tid < 256) asm volatile("s_waitcnt vmcnt(0)" ::: "memory");
            __syncthreads();
        }

        // ---- signal completion of iteration tau ----
        if (tid == 0)
            __hip_atomic_fetch_add(own_c, 1u, __ATOMIC_RELAXED, __HIP_MEMORY_SCOPE_AGENT);
    }
}

// ---------------- host ----------------
extern "C" void kernel_launch(void* const* d_in, const int* in_sizes, int n_in,
                              void* d_out, int out_size, void* d_ws, size_t ws_size,
                              hipStream_t stream) {
    const float* x     = (const float*)d_in[0];
    const int*   lens  = (const int*)d_in[1];     // int32 (JAX x64-disabled)
    const float* Wih_f = (const float*)d_in[2];
    const float* Whh_f = (const float*)d_in[3];
    const float* bih_f = (const float*)d_in[4];
    const float* bhh_f = (const float*)d_in[5];
    const float* Wih_b = (const float*)d_in[6];
    const float* Whh_b = (const float*)d_in[7];
    const float* bih_b = (const float*)d_in[8];
    const float* bhh_b = (const float*)d_in[9];
    float* out = (float*)d_out;
    char* ws = (char*)d_ws;
    if (ws_size < 89161984) return;

    unsigned short* xh    = (unsigned short*)(ws);                 // 26,214,400
    unsigned short* xl    = (unsigned short*)(ws + 26214400);      // 26,214,400
    unsigned short* wprep = (unsigned short*)(ws + 52428800);      // 33,554,432
    float*          bsum  = (float*)(ws + 85983232);               //     32,768
    unsigned short* hhi   = (unsigned short*)(ws + 86016000);      //  1,572,864
    unsigned short* hlo   = (unsigned short*)(ws + 87588864);      //  1,572,864
    unsigned*       ctr   = (unsigned*)(ws + 89161728);            //        256

    prep_x<<<6400, 256, 0, stream>>>(x, xh, xl);
    prep_w<<<1024, 256, 0, stream>>>(Wih_f, wprep, 0, 0);
    prep_w<<<1024, 256, 0, stream>>>(Whh_f, wprep, 0, 1);
    prep_w<<<1024, 256, 0, stream>>>(Wih_b, wprep, 1, 0);
    prep_w<<<1024, 256, 0, stream>>>(Whh_b, wprep, 1, 1);
    bsum_k<<<32, 256, 0, stream>>>(bih_f, bhh_f, bih_b, bhh_b, bsum);
    reset_k<<<769, 256, 0, stream>>>((uint4*)hhi);   // zeroes hhi | hlo | ctr (contiguous)

    static const int LDS_BYTES = 131072 + 16896 + 4224;  // 152,192
    hipFuncSetAttribute(reinterpret_cast<const void*>(lstm_persist),
                        hipFuncAttributeMaxDynamicSharedMemorySize, LDS_BYTES);

    void* args[] = {(void*)&xh, (void*)&xl, (void*)&wprep, (void*)&bsum,
                    (void*)&hhi, (void*)&hlo, (void*)&lens, (void*)&out, (void*)&ctr};
    hipLaunchCooperativeKernel(reinterpret_cast<void*>(lstm_persist),
                               dim3(256), dim3(512), args, LDS_BYTES, stream);
}